// Round 4
// baseline (211.356 us; speedup 1.0000x reference)
//
#include <hip/hip_runtime.h>

// x: [2,64,32,32,32] f32 | weight: [128,64,3,3,3] f32 | bias:[128]
// lora_A: [16,1728] | lora_B: [128,16] | out: [2,128,32,32,32] f32 | SCALING = 2.0
//
// prep:    x -> xt[b][34][34][34][64] bf16 (zero halo); weights+lora_A ->
//          wpack in MFMA-A-fragment order [(kb*2+ks)*9+nf][lane][8]
// gemm:    barrier-free LDS-free implicit GEMM, M=144 split 3-way across
//          blocks (3 frags each) for occupancy; 2-deep register pipeline.
//          Epilogue -> cbuf (bf16 conv+bias) + low.
// foldmix: per 64-position block: fold low -> fl[16][64] in LDS, then
//          out = cbuf + 2 * lora_B . fl

typedef __attribute__((ext_vector_type(8))) short short8;
typedef __attribute__((ext_vector_type(4))) float float4v;

#define PV 39304   // 34^3
#define PH 1156    // 34^2

__device__ inline unsigned short f2bf(float f) {
    unsigned int u = __float_as_uint(f);
    unsigned int r = u + 0x7FFFu + ((u >> 16) & 1u);
    return (unsigned short)(r >> 16);
}

// grid = 1024 (transpose) + 308 (halo zero) + 122 (weight pack)
__global__ __launch_bounds__(256) void prep_kernel(const float* __restrict__ x,
                                                   const float* __restrict__ weight,
                                                   const float* __restrict__ loraA,
                                                   unsigned short* __restrict__ xt,
                                                   unsigned short* __restrict__ wpack) {
    int t = threadIdx.x;
    int blk = blockIdx.x;
    if (blk < 1024) {
        __shared__ float tile[64][65];
        int b = blk >> 9;
        int p0 = (blk & 511) * 64;
        int d = p0 >> 10;
        int h0 = (p0 >> 5) & 31;
#pragma unroll
        for (int it = 0; it < 16; ++it) {
            int idx = it * 256 + t;
            int c = idx >> 6, pp = idx & 63;
            tile[c][pp] = x[((size_t)(b * 64 + c) << 15) + p0 + pp];
        }
        __syncthreads();
#pragma unroll
        for (int it = 0; it < 8; ++it) {
            int idx = it * 256 + t;
            int pp = idx >> 5, cp = idx & 31;
            unsigned int u0 = f2bf(tile[cp * 2][pp]);
            unsigned int u1 = f2bf(tile[cp * 2 + 1][pp]);
            int h = h0 + (pp >> 5);
            int w = pp & 31;
            size_t pidx = (size_t)((b * 34 + d + 1) * 34 + h + 1) * 34 + w + 1;
            *(unsigned int*)(xt + pidx * 64 + cp * 2) = u0 | (u1 << 16);
        }
    } else if (blk < 1332) {
        int idx = (blk - 1024) * 256 + t;     // over 2*39304 padded positions
        if (idx < 78608) {
            int b = idx / PV;
            int pp = idx - b * PV;
            int d = pp / PH;
            int r2 = pp - d * PH;
            int h = r2 / 34;
            int w = r2 - h * 34;
            if (d == 0 || d == 33 || h == 0 || h == 33 || w == 0 || w == 33) {
                uint4 z = {0u, 0u, 0u, 0u};
                uint4* dst = (uint4*)(xt + (size_t)idx * 64);
#pragma unroll
                for (int i = 0; i < 8; ++i) dst[i] = z;
            }
        }
    } else {
        int gid = (blk - 1332) * 256 + t;     // 486 frags * 64 lanes = 31104
        if (gid < 31104) {
            int frag = gid >> 6, lane = gid & 63;
            int kb = frag / 18;
            int r18 = frag - kb * 18;
            int ks = r18 / 9;
            int nf = r18 - ks * 9;
            int l16 = lane & 15, quad = lane >> 4;
            int n = nf * 16 + l16;
            int c0 = ks * 32 + quad * 8;
            unsigned int u[4];
#pragma unroll
            for (int jp = 0; jp < 4; ++jp) {
                int ca = c0 + jp * 2, cb = ca + 1;
                float v0, v1;
                if (n < 128) {
                    v0 = weight[(n * 64 + ca) * 27 + kb];
                    v1 = weight[(n * 64 + cb) * 27 + kb];
                } else {
                    v0 = loraA[(n - 128) * 1728 + ca * 27 + kb];
                    v1 = loraA[(n - 128) * 1728 + cb * 27 + kb];
                }
                u[jp] = (unsigned)f2bf(v0) | ((unsigned)f2bf(v1) << 16);
            }
            uint4 val; val.x = u[0]; val.y = u[1]; val.z = u[2]; val.w = u[3];
            *(uint4*)(wpack + (size_t)gid * 8) = val;
        }
    }
}

// 1536 blocks = 512 position-tiles x 3 M-groups (3 A-frags each).
// Wave = 1 h-row x 32 w (2 B-frags). Barrier-free, LDS-free, depth-2 pipeline.
__global__ __launch_bounds__(256, 5) void gemm_kernel(const unsigned short* __restrict__ xt,
                                                      const unsigned short* __restrict__ wpack,
                                                      const float* __restrict__ bias,
                                                      float* __restrict__ out,
                                                      unsigned short* __restrict__ cbuf,
                                                      float* __restrict__ low,
                                                      int use_cbuf) {
    int t = threadIdx.x;
    int wv = t >> 6;
    int lane = t & 63;
    int l16 = lane & 15;
    int quad = lane >> 4;

    int bid = blockIdx.x;            // 1536
    int tile = bid / 3;
    int mtype = bid - tile * 3;
    int f0 = mtype * 3;              // first of 3 A-frags

    int b = tile >> 8;
    int d = (tile >> 3) & 31;
    int h = (tile & 7) * 4 + wv;

    int pbase = (((b * 34 + d) * 34 + h) * 34 + l16) * 64 + quad * 8;
    int wbase = f0 * 512 + lane * 8;

    float4v acc[3][2];
#pragma unroll
    for (int nf = 0; nf < 3; ++nf)
#pragma unroll
        for (int f = 0; f < 2; ++f) acc[nf][f] = (float4v){0.f, 0.f, 0.f, 0.f};

    short8 b0[2], b1[2], a[2][3];

    auto loadstep = [&](int s, int buf) {
        int kb = s >> 1, ks = s & 1;
        int ki = kb / 9;
        int kjl = kb - ki * 9;
        int kj = kjl / 3;
        int kl = kjl - kj * 3;
        int koff = ki * 73984 + kj * 2176 + kl * 64 + ks * 32;
        const unsigned short* xp = xt + pbase + koff;
        b0[buf] = *(const short8*)xp;
        b1[buf] = *(const short8*)(xp + 1024);
        const unsigned short* wp = wpack + s * 4608 + wbase;
#pragma unroll
        for (int nf = 0; nf < 3; ++nf)
            a[buf][nf] = *(const short8*)(wp + nf * 512);
    };

    loadstep(0, 0);
    for (int s = 0; s < 54; s += 2) {
        loadstep(s + 1, 1);
#pragma unroll
        for (int nf = 0; nf < 3; ++nf) {
            acc[nf][0] = __builtin_amdgcn_mfma_f32_16x16x32_bf16(a[0][nf], b0[0], acc[nf][0], 0, 0, 0);
            acc[nf][1] = __builtin_amdgcn_mfma_f32_16x16x32_bf16(a[0][nf], b1[0], acc[nf][1], 0, 0, 0);
        }
        if (s + 2 < 54) loadstep(s + 2, 0);
#pragma unroll
        for (int nf = 0; nf < 3; ++nf) {
            acc[nf][0] = __builtin_amdgcn_mfma_f32_16x16x32_bf16(a[1][nf], b0[1], acc[nf][0], 0, 0, 0);
            acc[nf][1] = __builtin_amdgcn_mfma_f32_16x16x32_bf16(a[1][nf], b1[1], acc[nf][1], 0, 0, 0);
        }
    }

#pragma unroll
    for (int f = 0; f < 2; ++f) {
        int w = f * 16 + l16;
        int p = d * 1024 + h * 32 + w;
#pragma unroll
        for (int nf = 0; nf < 3; ++nf) {
#pragma unroll
            for (int r = 0; r < 4; ++r) {
                int o = (f0 + nf) * 16 + quad * 4 + r;
                float v = acc[nf][f][r];
                if (o < 128) {
                    float c = v + bias[o];
                    if (use_cbuf) cbuf[((size_t)(b * 128 + o) << 15) + p] = f2bf(c);
                    else          out[((size_t)(b * 128 + o) << 15) + p] = c;
                } else {
                    low[((size_t)(b * 16 + (o - 128)) << 15) + p] = v;
                }
            }
        }
    }
}

// 1024 blocks x 64 positions: fold low into LDS fl[16][64], then
// out[b][o][p] = conv(b,o,p) + 2 * sum_r lora_B[o][r] * fl[r][p]
__global__ __launch_bounds__(256) void foldmix_kernel(const float* __restrict__ low,
                                                      const float* __restrict__ loraB,
                                                      const unsigned short* __restrict__ cbuf,
                                                      float* __restrict__ out,
                                                      int use_cbuf) {
    __shared__ float fl[16][64];
    __shared__ float lB[2048];
    int t = threadIdx.x;
    for (int i = t; i < 2048; i += 256) lB[i] = loraB[i];

    int P0 = blockIdx.x * 64;
    int b = P0 >> 15;
    int p0 = P0 & 32767;

    {
        int pos = t & 63;
        int rg = t >> 6;           // r group: rg*4 .. rg*4+3
        int p = p0 + pos;
        int d = p >> 10, h = (p >> 5) & 31, w = p & 31;
        float s0 = 0.f, s1 = 0.f, s2 = 0.f, s3 = 0.f;
        const float* base = low + ((size_t)(b * 16 + rg * 4) << 15);
        for (int dd = -1; dd <= 1; ++dd) {
            int sd = d + dd;
            if ((unsigned)sd >= 32u) continue;
            for (int dh = -1; dh <= 1; ++dh) {
                int sh = h + dh;
                if ((unsigned)sh >= 32u) continue;
                for (int dw = -1; dw <= 1; ++dw) {
                    int sw = w + dw;
                    if ((unsigned)sw >= 32u) continue;
                    const float* q = base + (sd << 10) + (sh << 5) + sw;
                    s0 += q[0];
                    s1 += q[1 << 15];
                    s2 += q[2 << 15];
                    s3 += q[3 << 15];
                }
            }
        }
        fl[rg * 4 + 0][pos] = s0;
        fl[rg * 4 + 1][pos] = s1;
        fl[rg * 4 + 2][pos] = s2;
        fl[rg * 4 + 3][pos] = s3;
    }
    __syncthreads();

    int wv = t >> 6;
    int lane = t & 63;
    int p = p0 + lane;
    float f[16];
#pragma unroll
    for (int r = 0; r < 16; ++r) f[r] = fl[r][lane];

    int o0 = wv * 32;
#pragma unroll
    for (int oi = 0; oi < 32; ++oi) {
        int o = o0 + oi;
        float s = 0.f;
#pragma unroll
        for (int r = 0; r < 16; ++r) s += lB[o * 16 + r] * f[r];
        size_t idx = ((size_t)(b * 128 + o) << 15) + p;
        float c = use_cbuf ? __uint_as_float((unsigned)cbuf[idx] << 16) : out[idx];
        out[idx] = c + 2.0f * s;
    }
}

extern "C" void kernel_launch(void* const* d_in, const int* in_sizes, int n_in,
                              void* d_out, int out_size, void* d_ws, size_t ws_size,
                              hipStream_t stream) {
    const float* x      = (const float*)d_in[0];
    const float* weight = (const float*)d_in[1];
    const float* bias   = (const float*)d_in[2];
    const float* loraA  = (const float*)d_in[3];
    const float* loraB  = (const float*)d_in[4];
    float* out = (float*)d_out;

    char* ws = (char*)d_ws;
    unsigned short* xt    = (unsigned short*)ws;                  // 10,061,824 B
    unsigned short* wpack = (unsigned short*)(ws + 10061824);     //    497,664 B
    float* low            = (float*)(ws + 10559488);              //  4,194,304 B
    unsigned short* cbuf  = (unsigned short*)(ws + 14753792);     // 16,777,216 B
    int use_cbuf = (ws_size >= 31531008u) ? 1 : 0;

    hipLaunchKernelGGL(prep_kernel, dim3(1454), dim3(256), 0, stream, x, weight, loraA, xt, wpack);
    hipLaunchKernelGGL(gemm_kernel, dim3(1536), dim3(256), 0, stream, xt, wpack, bias, out, cbuf, low, use_cbuf);
    hipLaunchKernelGGL(foldmix_kernel, dim3(1024), dim3(256), 0, stream, low, loraB, cbuf, out, use_cbuf);
}

// Round 5
// 147.305 us; speedup vs baseline: 1.4348x; 1.4348x over previous
//
#include <hip/hip_runtime.h>

// x: [2,64,32,32,32] f32 | weight: [128,64,3,3,3] f32 | bias:[128]
// lora_A: [16,1728] | lora_B: [128,16] | out: [2,128,32,32,32] f32 | SCALING = 2.0

typedef __attribute__((ext_vector_type(8))) short short8;
typedef __attribute__((ext_vector_type(4))) float float4v;

#define PV 39304   // 34^3
#define PH 1156    // 34^2

__device__ inline unsigned short f2bf(float f) {
    unsigned int u = __float_as_uint(f);
    unsigned int r = u + 0x7FFFu + ((u >> 16) & 1u);
    return (unsigned short)(r >> 16);
}

__device__ inline void gll16(const void* g, void* l) {
    __builtin_amdgcn_global_load_lds(
        (const __attribute__((address_space(1))) unsigned int*)g,
        (__attribute__((address_space(3))) unsigned int*)l, 16, 0, 0);
}

// grid = 1024 (transpose) + 308 (halo zero) + 122 (weight pack)
__global__ __launch_bounds__(256) void prep_kernel(const float* __restrict__ x,
                                                   const float* __restrict__ weight,
                                                   const float* __restrict__ loraA,
                                                   unsigned short* __restrict__ xt,
                                                   unsigned short* __restrict__ wpack) {
    int t = threadIdx.x;
    int blk = blockIdx.x;
    if (blk < 1024) {
        __shared__ float tile[64][65];
        int b = blk >> 9;
        int p0 = (blk & 511) * 64;
        int d = p0 >> 10;
        int h0 = (p0 >> 5) & 31;
#pragma unroll
        for (int it = 0; it < 16; ++it) {
            int idx = it * 256 + t;
            int c = idx >> 6, pp = idx & 63;
            tile[c][pp] = x[((size_t)(b * 64 + c) << 15) + p0 + pp];
        }
        __syncthreads();
#pragma unroll
        for (int it = 0; it < 8; ++it) {
            int idx = it * 256 + t;
            int pp = idx >> 5, cp = idx & 31;
            unsigned int u0 = f2bf(tile[cp * 2][pp]);
            unsigned int u1 = f2bf(tile[cp * 2 + 1][pp]);
            int h = h0 + (pp >> 5);
            int w = pp & 31;
            size_t pidx = (size_t)((b * 34 + d + 1) * 34 + h + 1) * 34 + w + 1;
            *(unsigned int*)(xt + pidx * 64 + cp * 2) = u0 | (u1 << 16);
        }
    } else if (blk < 1332) {
        int idx = (blk - 1024) * 256 + t;     // over 2*39304 padded positions
        if (idx < 78608) {
            int b = idx / PV;
            int pp = idx - b * PV;
            int d = pp / PH;
            int r2 = pp - d * PH;
            int h = r2 / 34;
            int w = r2 - h * 34;
            if (d == 0 || d == 33 || h == 0 || h == 33 || w == 0 || w == 33) {
                uint4 z = {0u, 0u, 0u, 0u};
                uint4* dst = (uint4*)(xt + (size_t)idx * 64);
#pragma unroll
                for (int i = 0; i < 8; ++i) dst[i] = z;
            }
        }
    } else {
        int gid = (blk - 1332) * 256 + t;     // 486 frags * 64 lanes = 31104
        if (gid < 31104) {
            int frag = gid >> 6, lane = gid & 63;
            int kb = frag / 18;
            int r18 = frag - kb * 18;
            int ks = r18 / 9;
            int nf = r18 - ks * 9;
            int l16 = lane & 15, quad = lane >> 4;
            int n = nf * 16 + l16;
            int c0 = ks * 32 + quad * 8;
            unsigned int u[4];
#pragma unroll
            for (int jp = 0; jp < 4; ++jp) {
                int ca = c0 + jp * 2, cb = ca + 1;
                float v0, v1;
                if (n < 128) {
                    v0 = weight[(n * 64 + ca) * 27 + kb];
                    v1 = weight[(n * 64 + cb) * 27 + kb];
                } else {
                    v0 = loraA[(n - 128) * 1728 + ca * 27 + kb];
                    v1 = loraA[(n - 128) * 1728 + cb * 27 + kb];
                }
                u[jp] = (unsigned)f2bf(v0) | ((unsigned)f2bf(v1) << 16);
            }
            uint4 val; val.x = u[0]; val.y = u[1]; val.z = u[2]; val.w = u[3];
            *(uint4*)(wpack + (size_t)gid * 8) = val;
        }
    }
}

// 512 blocks x 4 waves. Wave = 1 h-row x 32 w, M = 144 (9 A-frags).
// A staged in LDS (dbuf, global_load_lds prefetch 1 tap ahead, shared by 4 waves);
// B per-lane global with register dbuf. Barrier per tap.
__global__ __launch_bounds__(256) void gemm_kernel(const unsigned short* __restrict__ xt,
                                                   const unsigned short* __restrict__ wpack,
                                                   const float* __restrict__ bias,
                                                   float* __restrict__ out,
                                                   unsigned short* __restrict__ cbuf,
                                                   float* __restrict__ low,
                                                   int use_cbuf) {
    __shared__ unsigned short Abuf[2][9216];   // 2 x 18432 B = tap's 18 frags

    int t = threadIdx.x;
    int wv = t >> 6;
    int lane = t & 63;
    int l16 = lane & 15;
    int quad = lane >> 4;

    int bid = blockIdx.x;                       // 512
    int tile = ((bid & 7) << 6) | (bid >> 3);   // XCD d-slab locality
    int b = tile >> 8;
    int d = (tile >> 3) & 31;
    int h = ((tile & 7) << 2) + wv;

    int pbase = (((b * 34 + d) * 34 + h) * 34 + l16) * 64 + quad * 8;

    float4v acc[9][2];
#pragma unroll
    for (int nf = 0; nf < 9; ++nf)
#pragma unroll
        for (int f = 0; f < 2; ++f) acc[nf][f] = (float4v){0.f, 0.f, 0.f, 0.f};

    short8 breg[2][2][2];    // [buf][ks][f]

    auto prefA = [&](int tap, int buf) {
        const unsigned short* src = wpack + tap * 9216;   // 18432 B per tap
        unsigned short* dst = &Abuf[buf][0];
#pragma unroll
        for (int j = 0; j < 4; ++j) {
            int c8 = (t + j * 256) * 8;
            gll16(src + c8, dst + c8);
        }
        if (t < 128) {
            int c8 = (t + 1024) * 8;
            gll16(src + c8, dst + c8);
        }
    };
    auto loadB = [&](int tap, int buf) {
        int ki = tap / 9;
        int kjl = tap - ki * 9;
        int kj = kjl / 3;
        int kl = kjl - kj * 3;
        int koff = ki * 73984 + kj * 2176 + kl * 64;
        const unsigned short* xp = xt + pbase + koff;
        breg[buf][0][0] = *(const short8*)(xp);
        breg[buf][0][1] = *(const short8*)(xp + 1024);
        breg[buf][1][0] = *(const short8*)(xp + 32);
        breg[buf][1][1] = *(const short8*)(xp + 1056);
    };

    prefA(0, 0);
    loadB(0, 0);
    __syncthreads();

    for (int tap = 0; tap < 27; ++tap) {
        int cur = tap & 1, nxt = cur ^ 1;
        if (tap < 26) {
            prefA(tap + 1, nxt);
            loadB(tap + 1, nxt);
        }
        const unsigned short* ab = &Abuf[cur][0] + lane * 8;
#pragma unroll
        for (int ks = 0; ks < 2; ++ks) {
            short8 af[9];
#pragma unroll
            for (int nf = 0; nf < 9; ++nf)
                af[nf] = *(const short8*)(ab + (ks * 9 + nf) * 512);
#pragma unroll
            for (int nf = 0; nf < 9; ++nf) {
                acc[nf][0] = __builtin_amdgcn_mfma_f32_16x16x32_bf16(af[nf], breg[cur][ks][0], acc[nf][0], 0, 0, 0);
                acc[nf][1] = __builtin_amdgcn_mfma_f32_16x16x32_bf16(af[nf], breg[cur][ks][1], acc[nf][1], 0, 0, 0);
            }
        }
        __syncthreads();
    }

#pragma unroll
    for (int f = 0; f < 2; ++f) {
        int w = f * 16 + l16;
        int p = d * 1024 + h * 32 + w;
#pragma unroll
        for (int nf = 0; nf < 9; ++nf) {
#pragma unroll
            for (int r = 0; r < 4; ++r) {
                int o = nf * 16 + quad * 4 + r;
                float v = acc[nf][f][r];
                if (o < 128) {
                    float c = v + bias[o];
                    if (use_cbuf) cbuf[((size_t)(b * 128 + o) << 15) + p] = f2bf(c);
                    else          out[((size_t)(b * 128 + o) << 15) + p] = c;
                } else {
                    low[((size_t)(b * 16 + (o - 128)) << 15) + p] = v;
                }
            }
        }
    }
}

// 512 blocks x 128 positions: fold low -> fl[16][128] (2 pos/thread, shared
// 4-wide w-window), then out = cbuf + 2 * lora_B . fl with float2 stores.
__global__ __launch_bounds__(256) void foldmix_kernel(const float* __restrict__ low,
                                                      const float* __restrict__ loraB,
                                                      const unsigned short* __restrict__ cbuf,
                                                      float* __restrict__ out,
                                                      int use_cbuf) {
    __shared__ float fl[16][128];
    __shared__ float lB[2048];
    int t = threadIdx.x;
    for (int i = t; i < 2048; i += 256) lB[i] = loraB[i];

    int P0 = blockIdx.x * 128;
    int b = P0 >> 15;
    int p0 = P0 & 32767;

    {
        int pair = t & 63;           // 2 consecutive w positions
        int rg = t >> 6;             // 4 ranks
        int p = p0 + pair * 2;
        int dd0 = p >> 10, hh = (p >> 5) & 31, w0 = p & 31;   // w0 even
        float s[4][2];
#pragma unroll
        for (int r = 0; r < 4; ++r) { s[r][0] = 0.f; s[r][1] = 0.f; }
        const float* bb = low + ((size_t)(b * 16 + rg * 4) << 15);
        for (int dd = -1; dd <= 1; ++dd) {
            int sd = dd0 + dd;
            if ((unsigned)sd >= 32u) continue;
            for (int dh = -1; dh <= 1; ++dh) {
                int sh = hh + dh;
                if ((unsigned)sh >= 32u) continue;
                int base = (sd << 10) + (sh << 5) + w0;
#pragma unroll
                for (int r = 0; r < 4; ++r) {
                    const float* q = bb + ((size_t)r << 15) + base;
                    float vm = (w0 > 0)  ? q[-1] : 0.f;
                    float v0 = q[0], v1 = q[1];
                    float v2 = (w0 < 30) ? q[2] : 0.f;
                    s[r][0] += vm + v0 + v1;
                    s[r][1] += v0 + v1 + v2;
                }
            }
        }
#pragma unroll
        for (int r = 0; r < 4; ++r) {
            fl[rg * 4 + r][pair * 2]     = s[r][0];
            fl[rg * 4 + r][pair * 2 + 1] = s[r][1];
        }
    }
    __syncthreads();

    int wv = t >> 6;
    int lane = t & 63;
    int pl = lane * 2;
    int p = p0 + pl;
    float2 f[16];
#pragma unroll
    for (int r = 0; r < 16; ++r) f[r] = *(const float2*)&fl[r][pl];

    int o0 = wv * 32;
#pragma unroll
    for (int oi = 0; oi < 32; ++oi) {
        int o = o0 + oi;
        float sa = 0.f, sb = 0.f;
#pragma unroll
        for (int r = 0; r < 16; ++r) {
            float lw = lB[o * 16 + r];
            sa += lw * f[r].x;
            sb += lw * f[r].y;
        }
        size_t idx = ((size_t)(b * 128 + o) << 15) + p;
        float cx, cy;
        if (use_cbuf) {
            unsigned int u = *(const unsigned int*)(cbuf + idx);
            cx = __uint_as_float(u << 16);
            cy = __uint_as_float(u & 0xffff0000u);
        } else {
            float2 c = *(const float2*)(out + idx);
            cx = c.x; cy = c.y;
        }
        float2 res;
        res.x = cx + 2.0f * sa;
        res.y = cy + 2.0f * sb;
        *(float2*)(out + idx) = res;
    }
}

extern "C" void kernel_launch(void* const* d_in, const int* in_sizes, int n_in,
                              void* d_out, int out_size, void* d_ws, size_t ws_size,
                              hipStream_t stream) {
    const float* x      = (const float*)d_in[0];
    const float* weight = (const float*)d_in[1];
    const float* bias   = (const float*)d_in[2];
    const float* loraA  = (const float*)d_in[3];
    const float* loraB  = (const float*)d_in[4];
    float* out = (float*)d_out;

    char* ws = (char*)d_ws;
    unsigned short* xt    = (unsigned short*)ws;                  // 10,061,824 B
    unsigned short* wpack = (unsigned short*)(ws + 10061824);     //    497,664 B
    float* low            = (float*)(ws + 10559488);              //  4,194,304 B
    unsigned short* cbuf  = (unsigned short*)(ws + 14753792);     // 16,777,216 B
    int use_cbuf = (ws_size >= 31531008u) ? 1 : 0;

    hipLaunchKernelGGL(prep_kernel, dim3(1454), dim3(256), 0, stream, x, weight, loraA, xt, wpack);
    hipLaunchKernelGGL(gemm_kernel, dim3(512), dim3(256), 0, stream, xt, wpack, bias, out, cbuf, low, use_cbuf);
    hipLaunchKernelGGL(foldmix_kernel, dim3(512), dim3(256), 0, stream, low, loraB, cbuf, out, use_cbuf);
}